// Round 2
// baseline (905.704 us; speedup 1.0000x reference)
//
#include <hip/hip_runtime.h>
#include <math.h>

// Problem: B=16, CI=CO=64, H=W=256, M1=M2=20 spectral conv (FNO layer).
// Only 40x20 frequency modes survive -> partial DFTs instead of full FFTs.
//
// All scratch lives inside d_out: 1024 slots of 65536 floats (=32768 float2).
// Slot float2 layout:
//   [    0.. 5120)  Z      [20 kx][256 h]   (stage 4 out, stage 5 in)
//   [ 5120.. 5920)  XF     [800 modes]      (stage 2 out, stage 3 in)
//   [ 5920.. 6720)  YF     [800 modes]      (stage 3 out, stage 4 in)
//   [ 6720..14912)  WP     two 4096 weight slices (repack out, stage 3 in)
//   [16384..21504)  XW     [20 kx][256 h]   (stage 1 out, stage 2 in)
// Stage 5 finally overwrites the whole slot with the real output.

#define NMODE 800
#define SLOTF 65536
#define SLOT2 32768
#define OFF_Z   0
#define OFF_XF  5120
#define OFF_YF  5920
#define OFF_WP  6720
#define OFF_XW  16384
#define TWOPI_256 0.024543692606170255f  // 2*pi/256

// ---------------- stage 0: weight repack ----------------
// Wp[j][io] = (w_re[io*400+m], w_im[io*400+m]),  j = arr*400 + m, io = i*64+o
__global__ __launch_bounds__(256) void k_repack(const float* __restrict__ w1re,
                                                const float* __restrict__ w1im,
                                                const float* __restrict__ w2re,
                                                const float* __restrict__ w2im,
                                                float* __restrict__ out) {
  __shared__ float2 tile[64 * 65];
  int bx = blockIdx.x;
  int arr = bx / 448;
  int rem = bx - arr * 448;
  int iot = rem / 7, mt = rem - iot * 7;
  const float* wre = arr ? w2re : w1re;
  const float* wim = arr ? w2im : w1im;
  int io0 = iot * 64, m0 = mt * 64;
  for (int idx = threadIdx.x; idx < 64 * 64; idx += 256) {
    int r = idx >> 6, c = idx & 63;
    if (m0 + c < 400) {
      int g = (io0 + r) * 400 + m0 + c;
      tile[r * 65 + c] = make_float2(wre[g], wim[g]);
    }
  }
  __syncthreads();
  for (int idx = threadIdx.x; idx < 64 * 64; idx += 256) {
    int c = idx >> 6;   // m within tile
    int r = idx & 63;   // io within tile
    int m = m0 + c;
    if (m < 400) {
      int j = arr * 400 + m;
      float2* dst = (float2*)out + (size_t)(j >> 1) * SLOT2 + OFF_WP + (j & 1) * 4096;
      dst[io0 + r] = tile[r * 65 + c];
    }
  }
}

// ---------------- stage 1: DFT along w ----------------
// Xw[bi][kx][h] = sum_w x[bi][h][w] * e^{-2pi i kx w / 256}, kx = 0..19
__global__ __launch_bounds__(320) void k_dftw(const float* __restrict__ x,
                                              float* __restrict__ out) {
  __shared__ float tile[256 * 33];   // 256 h rows x 32 w chunk (pad 33)
  __shared__ float2 tw[256];
  const int t = threadIdx.x;
  const int bi = blockIdx.x;
  for (int m = t; m < 256; m += 320) {
    float sv, cv;
    __sincosf((float)m * TWOPI_256, &sv, &cv);
    tw[m] = make_float2(cv, sv);
  }
  const float* xp = x + (size_t)bi * SLOTF;
  const int rg = t & 63;        // h group (h = rg + 64*r4)
  const int kg = t >> 6;        // 0..4 -> kx = kg*4 + j
  float ar[4][4], ai[4][4];
#pragma unroll
  for (int a = 0; a < 4; ++a)
#pragma unroll
    for (int b2 = 0; b2 < 4; ++b2) { ar[a][b2] = 0.f; ai[a][b2] = 0.f; }

  for (int wc = 0; wc < 8; ++wc) {
    __syncthreads();
    for (int idx = t; idx < 8192; idx += 320) {
      int r = idx >> 5, c = idx & 31;
      tile[r * 33 + c] = xp[r * 256 + wc * 32 + c];
    }
    __syncthreads();
    int mm[4];
#pragma unroll
    for (int j = 0; j < 4; ++j) mm[j] = ((wc * 32) * (kg * 4 + j)) & 255;
#pragma unroll 4
    for (int ww = 0; ww < 32; ++ww) {
      float v0 = tile[rg * 33 + ww];
      float v1 = tile[(rg + 64) * 33 + ww];
      float v2 = tile[(rg + 128) * 33 + ww];
      float v3 = tile[(rg + 192) * 33 + ww];
#pragma unroll
      for (int j = 0; j < 4; ++j) {
        float2 cs = tw[mm[j]];
        mm[j] = (mm[j] + kg * 4 + j) & 255;
        ar[0][j] += v0 * cs.x; ai[0][j] -= v0 * cs.y;
        ar[1][j] += v1 * cs.x; ai[1][j] -= v1 * cs.y;
        ar[2][j] += v2 * cs.x; ai[2][j] -= v2 * cs.y;
        ar[3][j] += v3 * cs.x; ai[3][j] -= v3 * cs.y;
      }
    }
  }
  float2* dst = (float2*)out + (size_t)bi * SLOT2 + OFF_XW;
#pragma unroll
  for (int r4 = 0; r4 < 4; ++r4)
#pragma unroll
    for (int j = 0; j < 4; ++j) {
      int kx = kg * 4 + j, h = rg + 64 * r4;
      dst[kx * 256 + h] = make_float2(ar[r4][j], ai[r4][j]);
    }
}

// ---------------- stage 2: DFT along h ----------------
// XF[bi][m] = sum_h Xw[bi][kx][h] * e^{-2pi i ky h/256}
// m = kyi*20+kx, ky = kyi<20 ? kyi : 216+kyi
__global__ __launch_bounds__(256) void k_dfth(float* __restrict__ out) {
  __shared__ float2 xw[20 * 258];
  const int t = threadIdx.x;
  const int bi = blockIdx.x;
  const float2* src = (const float2*)out + (size_t)bi * SLOT2 + OFF_XW;
  for (int idx = t; idx < 5120; idx += 256) {
    int kx = idx >> 8, h = idx & 255;
    xw[kx * 258 + h] = src[idx];
  }
  __syncthreads();
  float2* dst = (float2*)out + (size_t)bi * SLOT2 + OFF_XF;
  for (int m = t; m < NMODE; m += 256) {
    int kyi = m / 20, kx = m - kyi * 20;
    int ky = kyi < 20 ? kyi : 216 + kyi;
    float sr, cr;  // rotator e^{-2pi i ky/256}
    __sincosf((float)(ky & 255) * TWOPI_256, &sr, &cr);
    sr = -sr;
    float c = 1.f, s = 0.f, accr = 0.f, acci = 0.f;
    const float2* row = xw + kx * 258;
#pragma unroll 4
    for (int h = 0; h < 256; ++h) {
      float2 v = row[h];
      accr += v.x * c - v.y * s;
      acci += v.y * c + v.x * s;
      float cn = c * cr - s * sr;
      s = c * sr + s * cr;
      c = cn;
    }
    dst[m] = make_float2(accr, acci);
  }
}

// ---------------- stage 3: channel mix ----------------
// YF[bo][m] = sum_i XF[b*64+i][m] * W[m][i][o]
__global__ __launch_bounds__(256) void k_mix(float* __restrict__ out) {
  __shared__ float2 xm[1024];
  __shared__ float2 wm[4096];
  const int t = threadIdx.x;
  const int m = blockIdx.x;  // 0..799
  int kyi = m / 20, kx = m - kyi * 20;
  int j = (kyi < 20) ? (kyi * 20 + kx) : (400 + (kyi - 20) * 20 + kx);
  const float2* wp = (const float2*)out + (size_t)(j >> 1) * SLOT2 + OFF_WP + (j & 1) * 4096;
  for (int idx = t; idx < 4096; idx += 256) wm[idx] = wp[idx];
  for (int bi = t; bi < 1024; bi += 256)
    xm[bi] = *((const float2*)out + (size_t)bi * SLOT2 + OFF_XF + m);
  __syncthreads();
#pragma unroll
  for (int k = 0; k < 4; ++k) {
    int bo = t + k * 256;
    int b = bo >> 6;
    int o = bo & 63;
    float accr = 0.f, acci = 0.f;
#pragma unroll 4
    for (int i = 0; i < 64; ++i) {
      float2 xv = xm[b * 64 + i];
      float2 wv = wm[i * 64 + o];
      accr += xv.x * wv.x - xv.y * wv.y;
      acci += xv.x * wv.y + xv.y * wv.x;
    }
    *((float2*)out + (size_t)bo * SLOT2 + OFF_YF + m) = make_float2(accr, acci);
  }
}

// ---------------- stage 4: inverse DFT along h ----------------
// Z[bo][kx][h] = sum_{kyi} YF[bo][kyi*20+kx] * e^{+2pi i ky h/256}
__global__ __launch_bounds__(256) void k_idfth(float* __restrict__ out) {
  __shared__ float2 y[NMODE];
  const int t = threadIdx.x;
  const int bo = blockIdx.x;
  const float2* src = (const float2*)out + (size_t)bo * SLOT2 + OFF_YF;
  for (int idx = t; idx < NMODE; idx += 256) y[idx] = src[idx];
  __syncthreads();
  const int hg = t & 63;
  const int kg = t >> 6;  // kx = kg + 4*q
  float zr[4][5], zi[4][5];
#pragma unroll
  for (int r = 0; r < 4; ++r)
#pragma unroll
    for (int q = 0; q < 5; ++q) { zr[r][q] = 0.f; zi[r][q] = 0.f; }
  float c[4], s[4], ch[4], sh[4];
#pragma unroll
  for (int r = 0; r < 4; ++r) {
    int h = hg + 64 * r;
    __sincosf((float)((h) & 255) * TWOPI_256, &sh[r], &ch[r]);  // e^{+2pi i h/256}
    c[r] = 1.f; s[r] = 0.f;
  }
  for (int kyi = 0; kyi < 40; ++kyi) {
    if (kyi == 20) {
#pragma unroll
      for (int r = 0; r < 4; ++r) {
        int h = hg + 64 * r;
        int mm = (236 * h) & 255;
        __sincosf((float)mm * TWOPI_256, &s[r], &c[r]);
      }
    }
#pragma unroll
    for (int q = 0; q < 5; ++q) {
      int kx = kg + 4 * q;
      float2 yv = y[kyi * 20 + kx];
#pragma unroll
      for (int r = 0; r < 4; ++r) {
        zr[r][q] += yv.x * c[r] - yv.y * s[r];
        zi[r][q] += yv.x * s[r] + yv.y * c[r];
      }
    }
#pragma unroll
    for (int r = 0; r < 4; ++r) {
      float cn = c[r] * ch[r] - s[r] * sh[r];
      s[r] = c[r] * sh[r] + s[r] * ch[r];
      c[r] = cn;
    }
  }
  float2* dst = (float2*)out + (size_t)bo * SLOT2 + OFF_Z;
#pragma unroll
  for (int r = 0; r < 4; ++r)
#pragma unroll
    for (int q = 0; q < 5; ++q) {
      int kx = kg + 4 * q, h = hg + 64 * r;
      dst[kx * 256 + h] = make_float2(zr[r][q], zi[r][q]);
    }
}

// ---------------- stage 5: inverse DFT along w + scale ----------------
// out[bo][h][w] = (1/65536) * [ Re(Z[0][h]) + 2*sum_{kx>=1} Re(Z[kx][h] e^{+2pi i kx w/256}) ]
__global__ __launch_bounds__(256) void k_idftw(float* __restrict__ out) {
  __shared__ float2 z[5120];
  __shared__ float2 tw[256];
  const int t = threadIdx.x;
  const int bo = blockIdx.x;
  {
    float sv, cv;
    __sincosf((float)t * TWOPI_256, &sv, &cv);
    tw[t] = make_float2(cv, sv);
  }
  const float2* src = (const float2*)out + (size_t)bo * SLOT2 + OFF_Z;
  for (int idx = t; idx < 5120; idx += 256) z[idx] = src[idx];
  __syncthreads();
  const int l = t & 63;   // w base; handles w = l, l+64, l+128, l+192 via i^kx rotations
  const int wv = t >> 6;  // h block
  float cw[20], sw[20];
#pragma unroll
  for (int kx = 0; kx < 20; ++kx) {
    float2 cs = tw[(kx * l) & 255];
    float sc = (kx == 0 ? 1.f : 2.f) * (1.f / 65536.f);
    cw[kx] = cs.x * sc;
    sw[kx] = cs.y * sc;
  }
  float* dst = out + (size_t)bo * SLOTF;
  for (int jh = 0; jh < 64; ++jh) {
    int h = wv * 64 + jh;
    float a0 = 0.f, a1 = 0.f, a2 = 0.f, a3 = 0.f;
#pragma unroll
    for (int kx = 0; kx < 20; ++kx) {
      float2 zv = z[kx * 256 + h];
      float av = zv.x * cw[kx] - zv.y * sw[kx];
      float bv = zv.x * sw[kx] + zv.y * cw[kx];
      a0 += av;
      if ((kx & 3) == 0)      { a1 += av; a2 += av; a3 += av; }
      else if ((kx & 3) == 1) { a1 -= bv; a2 -= av; a3 += bv; }
      else if ((kx & 3) == 2) { a1 -= av; a2 += av; a3 -= av; }
      else                    { a1 += bv; a2 -= av; a3 -= bv; }
    }
    dst[h * 256 + l]       = a0;
    dst[h * 256 + l + 64]  = a1;
    dst[h * 256 + l + 128] = a2;
    dst[h * 256 + l + 192] = a3;
  }
}

extern "C" void kernel_launch(void* const* d_in, const int* in_sizes, int n_in,
                              void* d_out, int out_size, void* d_ws, size_t ws_size,
                              hipStream_t stream) {
  const float* x    = (const float*)d_in[0];
  const float* w1re = (const float*)d_in[1];
  const float* w1im = (const float*)d_in[2];
  const float* w2re = (const float*)d_in[3];
  const float* w2im = (const float*)d_in[4];
  float* out = (float*)d_out;
  hipLaunchKernelGGL(k_repack, dim3(896), dim3(256), 0, stream, w1re, w1im, w2re, w2im, out);
  hipLaunchKernelGGL(k_dftw,   dim3(1024), dim3(320), 0, stream, x, out);
  hipLaunchKernelGGL(k_dfth,   dim3(1024), dim3(256), 0, stream, out);
  hipLaunchKernelGGL(k_mix,    dim3(800),  dim3(256), 0, stream, out);
  hipLaunchKernelGGL(k_idfth,  dim3(1024), dim3(256), 0, stream, out);
  hipLaunchKernelGGL(k_idftw,  dim3(1024), dim3(256), 0, stream, out);
}